// Round 6
// baseline (168.734 us; speedup 1.0000x reference)
//
#include <hip/hip_runtime.h>
#include <math.h>

// Problem constants (B,T,E,H fixed by setup_inputs).
constexpr int B_ = 8, T_ = 2048, E_ = 1024, H_ = 64;
constexpr long BT = (long)B_ * T_;   // 16384 rows

typedef __attribute__((ext_vector_type(8))) short bf16x8;   // 8 bf16 (4 VGPRs)
typedef __attribute__((ext_vector_type(4))) float f32x4;    // MFMA 16x16 acc

__device__ inline unsigned short bf16_rne(float f) {
    union { float f; unsigned u; } v; v.f = f;
    unsigned u = v.u + (0x7FFFu + ((v.u >> 16) & 1u));
    return (unsigned short)(u >> 16);
}
__device__ inline unsigned pack_bf16x2(float lo, float hi) {
    return (unsigned)bf16_rne(lo) | ((unsigned)bf16_rne(hi) << 16);
}

constexpr float QS = 0.18033688011112042f;   // H^-0.5 * log2(e), folded into Wq

// ====================================================================
// Kernel 0: build B-frag-ready transposed bf16 weight buffer. (R3)
// ====================================================================
__global__ __launch_bounds__(256) void wt_build_k(
    const float* __restrict__ Wk, const float* __restrict__ Wq,
    const float* __restrict__ Wv, unsigned short* __restrict__ Wt)
{
    const int d    = blockIdx.x * 256 + threadIdx.x;   // 0..24575
    const int tile = d >> 6;
    const int lq   = d & 63;
    const int quad = lq >> 4;
    const int l16  = lq & 15;
    const int kc   = tile / 12;
    const int nt   = tile - kc * 12;
    const int n    = nt * 16 + l16;

    const float* src; int col; float s = 1.0f;
    if (n < 64)       { src = Wk; col = n; }
    else if (n < 128) { src = Wq; col = n - 64; s = QS; }
    else              { src = Wv; col = n - 128; }

    const int kk0 = kc * 32 + quad * 8;
    const float* sp = src + (size_t)kk0 * H_ + col;
    unsigned p[4];
    #pragma unroll
    for (int jj = 0; jj < 4; jj++)
        p[jj] = pack_bf16x2(sp[(2 * jj) * H_] * s, sp[(2 * jj + 1) * H_] * s);
    *(uint4*)(Wt + (size_t)d * 8) = make_uint4(p[0], p[1], p[2], p[3]);
}

// ====================================================================
// Kernel 1: MFMA QKV projection, R6: 512 threads / 8 waves per block.
// Wave = 16 rows x 3 n-tiles (was 16x6): 2 blocks/CU x 8 waves =
// 16 waves/CU (2x R5) to cover ~900cyc HBM latency on x loads.
// __launch_bounds__(512,4) caps VGPR at 128 so the 1-deep prefetch
// survives register allocation (R5: VGPR=60 proved it was sunk).
// Block keeps 32 rows (full 32-key V tile required by the Vf
// key-pairing i <-> i+16). Epilogue unchanged from R5.
// ====================================================================
__global__ __launch_bounds__(512, 4) void qkv_mfma_k(
    const float* __restrict__ x, const unsigned short* __restrict__ Wt,
    unsigned short* __restrict__ kO, unsigned short* __restrict__ qO,
    unsigned short* __restrict__ vfO)
{
    __shared__ unsigned short VL[32][66];   // V tile staging (pad 66)

    const int t    = threadIdx.x;           // 0..511
    const int w    = t >> 6;                // 0..7
    const int l    = t & 63;
    const int l16  = l & 15;
    const int quad = l >> 4;
    const int rg   = w >> 2;                // row-group 0..1
    const int nq   = w & 3;                 // n-quarter 0..3 (3 tiles each)
    const int row0 = blockIdx.x * 32 + rg * 16;

    const float* xp = x + (size_t)(row0 + l16) * E_ + quad * 8;
    const unsigned short* wp = Wt + (size_t)(nq * 3) * 512 + (size_t)l * 8;

    f32x4 acc[3];
    #pragma unroll
    for (int n = 0; n < 3; n++) acc[n] = (f32x4){0.f, 0.f, 0.f, 0.f};

    // prefetch kc=0
    float4 a0 = *(const float4*)(xp);
    float4 a1 = *(const float4*)(xp + 4);
    bf16x8 bf[3];
    #pragma unroll
    for (int n = 0; n < 3; n++) bf[n] = *(const bf16x8*)(wp + (size_t)n * 512);

    for (int kc = 0; kc < 32; ++kc) {
        const int kn = (kc + 1) & 31;   // wrap: in-bounds, last iter harmless
        float4 na0 = *(const float4*)(xp + kn * 32);
        float4 na1 = *(const float4*)(xp + kn * 32 + 4);
        bf16x8 nb[3];
        #pragma unroll
        for (int n = 0; n < 3; n++)
            nb[n] = *(const bf16x8*)(wp + (size_t)(kn * 12 + n) * 512);

        union { bf16x8 v; unsigned u[4]; } av;
        av.u[0] = pack_bf16x2(a0.x, a0.y);
        av.u[1] = pack_bf16x2(a0.z, a0.w);
        av.u[2] = pack_bf16x2(a1.x, a1.y);
        av.u[3] = pack_bf16x2(a1.z, a1.w);

        #pragma unroll
        for (int n = 0; n < 3; n++)
            acc[n] = __builtin_amdgcn_mfma_f32_16x16x32_bf16(av.v, bf[n], acc[n], 0, 0, 0);

        a0 = na0; a1 = na1;
        #pragma unroll
        for (int n = 0; n < 3; n++) bf[n] = nb[n];
    }

    // ---- epilogue part 1: k/q global stores, v -> LDS staging ----
    #pragma unroll
    for (int n = 0; n < 3; n++) {
        const int gn = nq * 3 + n;          // 0..11
        const int hb = gn * 16 + l16;
        if (gn < 4) {                       // k columns 0..63
            #pragma unroll
            for (int r = 0; r < 4; r++) {
                const int row = row0 + quad * 4 + r;
                kO[(size_t)row * H_ + hb] = bf16_rne(acc[n][r]);
            }
        } else if (gn < 8) {                // q columns 0..63 (pre-scaled)
            #pragma unroll
            for (int r = 0; r < 4; r++) {
                const int row = row0 + quad * 4 + r;
                qO[(size_t)row * H_ + (hb - 64)] = bf16_rne(acc[n][r]);
            }
        } else {                            // v -> LDS tile [key-in-tile][h]
            #pragma unroll
            for (int r = 0; r < 4; r++)
                VL[rg * 16 + quad * 4 + r][(gn - 8) * 16 + l16] = bf16_rne(acc[n][r]);
        }
    }
    __syncthreads();

    // ---- epilogue part 2: gather permuted frags, coalesced Vf store ----
    if (t < 256) {
        const int g  = t >> 6;          // h-group 0..3
        const int lf = t & 15;
        const int qf = (t >> 4) & 3;
        unsigned pk[4];
        #pragma unroll
        for (int jj = 0; jj < 4; jj++) {
            const int p0 = qf * 8 + 2 * jj;
            const int i0 = (p0 >> 1) | ((p0 & 1) << 4);
            const int p1 = p0 + 1;
            const int i1 = (p1 >> 1) | ((p1 & 1) << 4);
            pk[jj] = (unsigned)VL[i0][g * 16 + lf]
                   | ((unsigned)VL[i1][g * 16 + lf] << 16);
        }
        const int tile = blockIdx.x;    // = b*64 + kt
        *(uint4*)(vfO + ((size_t)tile * 4 + g) * 512 + (size_t)(t & 63) * 8) =
            make_uint4(pk[0], pk[1], pk[2], pk[3]);
    }
}

// ====================================================================
// Kernel 2: MFMA flash attention (R5, unchanged): unnormalized exp2
// softmax, per-lane lsum, split-K x4 waves, fragment-major Vf loads.
// ====================================================================
__global__ __launch_bounds__(256, 4) void attn_mfma(
    const unsigned short* __restrict__ q,   // bf16 [B][T][H], pre-scaled
    const unsigned short* __restrict__ k,   // bf16 [B][T][H]
    const unsigned short* __restrict__ vf,  // bf16 fragment-major
    float* __restrict__ out)
{
    __shared__ unsigned short Pl[4][16 * 40];
    __shared__ float Ot[4][16][68];
    __shared__ float lsW[4][16];

    const int t    = threadIdx.x;
    const int w    = t >> 6;
    const int l    = t & 63;
    const int l16  = l & 15;
    const int quad = l >> 4;

    const int b    = blockIdx.x & 7;
    const int qidx = blockIdx.x >> 3;
    const int qt   = (qidx & 1) ? (127 - (qidx >> 1)) : (qidx >> 1);
    const int t0   = qt * 16;
    const int nk   = t0 / 32 + 1;

    const size_t qoff = ((size_t)b * T_ + t0 + l16) * H_ + quad * 8;
    bf16x8 aq0 = *(const bf16x8*)(q + qoff);
    bf16x8 aq1 = *(const bf16x8*)(q + qoff + 32);

    f32x4 o[4];
    #pragma unroll
    for (int g = 0; g < 4; g++) o[g] = (f32x4){0.f, 0.f, 0.f, 0.f};
    float ls[4] = {0.f, 0.f, 0.f, 0.f};

    const unsigned short* kbp = k + (size_t)b * T_ * H_;
    const unsigned short* vbp = vf + (size_t)b * 64 * 2048 + (size_t)l * 8;
    unsigned short* Pw = &Pl[w][0];

    bf16x8 bk00, bk01, bk10, bk11, bv0, bv1, bv2, bv3;
    if (w < nk) {
        const int kbase = w * 32;
        const unsigned short* kp = kbp + (size_t)(kbase + l16) * H_ + quad * 8;
        bk00 = *(const bf16x8*)(kp);
        bk01 = *(const bf16x8*)(kp + 32);
        bk10 = *(const bf16x8*)(kp + 16 * H_);
        bk11 = *(const bf16x8*)(kp + 16 * H_ + 32);
        const unsigned short* vp = vbp + (size_t)w * 2048;
        bv0 = *(const bf16x8*)(vp);
        bv1 = *(const bf16x8*)(vp + 512);
        bv2 = *(const bf16x8*)(vp + 1024);
        bv3 = *(const bf16x8*)(vp + 1536);
    }

    for (int kt = w; kt < nk; kt += 4) {
        const int ktn    = (kt + 4 < nk) ? kt + 4 : kt;
        const int kbasen = ktn * 32;
        const unsigned short* kpn = kbp + (size_t)(kbasen + l16) * H_ + quad * 8;
        bf16x8 nk00 = *(const bf16x8*)(kpn);
        bf16x8 nk01 = *(const bf16x8*)(kpn + 32);
        bf16x8 nk10 = *(const bf16x8*)(kpn + 16 * H_);
        bf16x8 nk11 = *(const bf16x8*)(kpn + 16 * H_ + 32);
        const unsigned short* vpn = vbp + (size_t)ktn * 2048;
        bf16x8 nv0 = *(const bf16x8*)(vpn);
        bf16x8 nv1 = *(const bf16x8*)(vpn + 512);
        bf16x8 nv2 = *(const bf16x8*)(vpn + 1024);
        bf16x8 nv3 = *(const bf16x8*)(vpn + 1536);

        const int kbase = kt * 32;
        f32x4 s0 = (f32x4){0.f, 0.f, 0.f, 0.f};
        f32x4 s1 = (f32x4){0.f, 0.f, 0.f, 0.f};
        s0 = __builtin_amdgcn_mfma_f32_16x16x32_bf16(aq0, bk00, s0, 0, 0, 0);
        s0 = __builtin_amdgcn_mfma_f32_16x16x32_bf16(aq1, bk01, s0, 0, 0, 0);
        s1 = __builtin_amdgcn_mfma_f32_16x16x32_bf16(aq0, bk10, s1, 0, 0, 0);
        s1 = __builtin_amdgcn_mfma_f32_16x16x32_bf16(aq1, bk11, s1, 0, 0, 0);

        if (kbase + 31 > t0) {
            const int rowb = t0 + quad * 4;
            #pragma unroll
            for (int r = 0; r < 4; r++) {
                if (kbase + l16 > rowb + r)      s0[r] = -3.0e38f;
                if (kbase + 16 + l16 > rowb + r) s1[r] = -3.0e38f;
            }
        }

        #pragma unroll
        for (int r = 0; r < 4; r++) {
            float p0 = exp2f(s0[r]);
            float p1 = exp2f(s1[r]);
            ls[r] += p0 + p1;
            *(unsigned*)(Pw + (quad * 4 + r) * 40 + 2 * l16) = pack_bf16x2(p0, p1);
        }
        asm volatile("s_waitcnt lgkmcnt(0)" ::: "memory");
        bf16x8 ap = *(const bf16x8*)(Pw + l16 * 40 + quad * 8);

        o[0] = __builtin_amdgcn_mfma_f32_16x16x32_bf16(ap, bv0, o[0], 0, 0, 0);
        o[1] = __builtin_amdgcn_mfma_f32_16x16x32_bf16(ap, bv1, o[1], 0, 0, 0);
        o[2] = __builtin_amdgcn_mfma_f32_16x16x32_bf16(ap, bv2, o[2], 0, 0, 0);
        o[3] = __builtin_amdgcn_mfma_f32_16x16x32_bf16(ap, bv3, o[3], 0, 0, 0);

        bk00 = nk00; bk01 = nk01; bk10 = nk10; bk11 = nk11;
        bv0 = nv0; bv1 = nv1; bv2 = nv2; bv3 = nv3;
    }

    #pragma unroll
    for (int r = 0; r < 4; r++) {
        float s = ls[r];
        s += __shfl_xor(s, 1);
        s += __shfl_xor(s, 2);
        s += __shfl_xor(s, 4);
        s += __shfl_xor(s, 8);
        ls[r] = s;
    }
    if (l16 == 0) {
        #pragma unroll
        for (int r = 0; r < 4; r++) lsW[w][quad * 4 + r] = ls[r];
    }
    #pragma unroll
    for (int g = 0; g < 4; g++)
        #pragma unroll
        for (int r = 0; r < 4; r++)
            Ot[w][quad * 4 + r][g * 16 + l16] = o[g][r];
    __syncthreads();

    {
        const int col = w * 16 + l16;
        #pragma unroll
        for (int r = 0; r < 4; r++) {
            const int row = quad * 4 + r;
            float L  = lsW[0][row] + lsW[1][row] + lsW[2][row] + lsW[3][row];
            float sv = Ot[0][row][col] + Ot[1][row][col]
                     + Ot[2][row][col] + Ot[3][row][col];
            out[((size_t)b * T_ + t0 + row) * H_ + col] = sv / L;
        }
    }
}

// ====================================================================
extern "C" void kernel_launch(void* const* d_in, const int* in_sizes, int n_in,
                              void* d_out, int out_size, void* d_ws, size_t ws_size,
                              hipStream_t stream)
{
    const float* x  = (const float*)d_in[0];
    const float* Wk = (const float*)d_in[1];
    const float* Wq = (const float*)d_in[2];
    const float* Wv = (const float*)d_in[3];

    // workspace: Wt (384KB) | k | q | vf (bf16, 2MB each)
    unsigned short* wt    = (unsigned short*)d_ws;
    unsigned short* kbuf  = wt + 24576 * 8;
    unsigned short* qbuf  = kbuf + BT * H_;
    unsigned short* vfbuf = qbuf + BT * H_;
    float* outp = (float*)d_out;

    wt_build_k<<<96, 256, 0, stream>>>(Wk, Wq, Wv, wt);
    qkv_mfma_k<<<(B_ * T_) / 32, 512, 0, stream>>>(x, wt, kbuf, qbuf, vfbuf);
    attn_mfma<<<B_ * 128, 256, 0, stream>>>(qbuf, kbuf, vfbuf, outp);
}

// Round 7
// 149.963 us; speedup vs baseline: 1.1252x; 1.1252x over previous
//
#include <hip/hip_runtime.h>
#include <math.h>

// Problem constants (B,T,E,H fixed by setup_inputs).
constexpr int B_ = 8, T_ = 2048, E_ = 1024, H_ = 64;
constexpr long BT = (long)B_ * T_;   // 16384 rows

typedef __attribute__((ext_vector_type(8))) short bf16x8;   // 8 bf16 (4 VGPRs)
typedef __attribute__((ext_vector_type(4))) float f32x4;    // MFMA 16x16 acc

__device__ inline unsigned short bf16_rne(float f) {
    union { float f; unsigned u; } v; v.f = f;
    unsigned u = v.u + (0x7FFFu + ((v.u >> 16) & 1u));
    return (unsigned short)(u >> 16);
}
__device__ inline unsigned pack_bf16x2(float lo, float hi) {
    return (unsigned)bf16_rne(lo) | ((unsigned)bf16_rne(hi) << 16);
}

// Async global->LDS DMA, 16B per lane. LDS dest is wave-uniform base +
// lane*16 (HW requirement) — callers must pass lane-contiguous dests.
// AS casts via integer round-trip (flat->LDS offset = low 32 bits on gfx9+).
__device__ inline void load_lds16(const void* g, void* l) {
    __builtin_amdgcn_global_load_lds(
        (const __attribute__((address_space(1))) void*)(uintptr_t)g,
        (__attribute__((address_space(3))) void*)(unsigned)(uintptr_t)l,
        16, 0, 0);
}

constexpr float QS = 0.18033688011112042f;   // H^-0.5 * log2(e), folded into Wq

// ====================================================================
// Kernel 0: build B-frag-ready transposed bf16 weight buffer. (R3)
// ====================================================================
__global__ __launch_bounds__(256) void wt_build_k(
    const float* __restrict__ Wk, const float* __restrict__ Wq,
    const float* __restrict__ Wv, unsigned short* __restrict__ Wt)
{
    const int d    = blockIdx.x * 256 + threadIdx.x;   // 0..24575
    const int tile = d >> 6;
    const int lq   = d & 63;
    const int quad = lq >> 4;
    const int l16  = lq & 15;
    const int kc   = tile / 12;
    const int nt   = tile - kc * 12;
    const int n    = nt * 16 + l16;

    const float* src; int col; float s = 1.0f;
    if (n < 64)       { src = Wk; col = n; }
    else if (n < 128) { src = Wq; col = n - 64; s = QS; }
    else              { src = Wv; col = n - 128; }

    const int kk0 = kc * 32 + quad * 8;
    const float* sp = src + (size_t)kk0 * H_ + col;
    unsigned p[4];
    #pragma unroll
    for (int jj = 0; jj < 4; jj++)
        p[jj] = pack_bf16x2(sp[(2 * jj) * H_] * s, sp[(2 * jj + 1) * H_] * s);
    *(uint4*)(Wt + (size_t)d * 8) = make_uint4(p[0], p[1], p[2], p[3]);
}

// ====================================================================
// Kernel 1: MFMA QKV projection, R7: global_load_lds staged x.
// R5/R6 post-mortem: compiler sinks register prefetch (VGPR=60/36),
// leaving serial HBM round-trips per iter (~1800 cyc/wave-iter).
// Fix: async DMA staging (no VGPR dest -> cannot be sunk; drained by
// the barrier). 512 blocks x 512 thr (8 waves, 2 blocks/CU).
// Block = 32 rows x 192 cols. K-loop: 16 iters of BK=64, double-
// buffered 8KB x-tiles; each wave issues ONE 1KB DMA call per iter.
// LDS chunk-XOR swizzle ([r][c] holds global chunk c^(r&7)) keeps
// ds_read_b128 at the 8-lane/bank-group floor. A-frags packed fp32->
// bf16 in-register (numerics identical to R5/R6). Wt b-frags direct
// from L2. Epilogue (k/q stores + VL->Vf permute) unchanged from R6.
// ====================================================================
__global__ __launch_bounds__(512, 4) void qkv_mfma_k(
    const float* __restrict__ x, const unsigned short* __restrict__ Wt,
    unsigned short* __restrict__ kO, unsigned short* __restrict__ qO,
    unsigned short* __restrict__ vfO)
{
    __shared__ float4 xs[2][32][16];        // 16 KB: [buf][row][chunk], swizzled
    __shared__ unsigned short VL[32][66];   // V tile staging (pad 66)

    const int t    = threadIdx.x;           // 0..511
    const int w    = t >> 6;                // 0..7
    const int l    = t & 63;
    const int l16  = l & 15;
    const int quad = l >> 4;
    const int rg   = w >> 2;                // row-group 0..1
    const int nq   = w & 3;                 // n-quarter 0..3 (3 tiles each)
    const int row0 = blockIdx.x * 32 + rg * 16;
    const int row0b = blockIdx.x * 32;

    // ---- DMA lane mapping (fixed): wave w stages rows w*4..w*4+3 ----
    const int rr = w * 4 + (l >> 4);        // staged row 0..31
    const int cc = l & 15;                  // LDS chunk slot
    const int gg = cc ^ (rr & 7);           // global chunk fetched (swizzle)
    const float* gsrc = x + (size_t)(row0b + rr) * E_ + gg * 4;
    // LDS dest offset (float4 units) = rr*16+cc = w*64 + l -> lane-contiguous ✓

    // ---- reader mapping ----
    const int r  = rg * 16 + l16;           // A-frag row in tile
    const int rx = r & 7;                   // swizzle key

    f32x4 acc[3];
    #pragma unroll
    for (int n = 0; n < 3; n++) acc[n] = (f32x4){0.f, 0.f, 0.f, 0.f};

    load_lds16(gsrc, &xs[0][rr][cc]);       // stage tile 0

    for (int it = 0; it < 16; ++it) {
        const int buf = it & 1;
        __syncthreads();                    // drains tile-it DMA (vmcnt) + prev reads
        if (it + 1 < 16)
            load_lds16(gsrc + (it + 1) * 64, &xs[buf ^ 1][rr][cc]);

        #pragma unroll
        for (int kk = 0; kk < 2; ++kk) {
            const int G0 = kk * 8 + quad * 2;
            float4 fa = xs[buf][r][G0 ^ rx];
            float4 fb = xs[buf][r][(G0 + 1) ^ rx];

            const int kc = it * 2 + kk;
            const unsigned short* wpp = Wt + (size_t)(kc * 12 + nq * 3) * 512 + (size_t)l * 8;
            bf16x8 b0 = *(const bf16x8*)(wpp);
            bf16x8 b1 = *(const bf16x8*)(wpp + 512);
            bf16x8 b2 = *(const bf16x8*)(wpp + 1024);

            union { bf16x8 v; unsigned u[4]; } av;
            av.u[0] = pack_bf16x2(fa.x, fa.y);
            av.u[1] = pack_bf16x2(fa.z, fa.w);
            av.u[2] = pack_bf16x2(fb.x, fb.y);
            av.u[3] = pack_bf16x2(fb.z, fb.w);

            acc[0] = __builtin_amdgcn_mfma_f32_16x16x32_bf16(av.v, b0, acc[0], 0, 0, 0);
            acc[1] = __builtin_amdgcn_mfma_f32_16x16x32_bf16(av.v, b1, acc[1], 0, 0, 0);
            acc[2] = __builtin_amdgcn_mfma_f32_16x16x32_bf16(av.v, b2, acc[2], 0, 0, 0);
        }
    }

    // ---- epilogue part 1: k/q global stores, v -> LDS staging (R6) ----
    #pragma unroll
    for (int n = 0; n < 3; n++) {
        const int gn = nq * 3 + n;          // 0..11
        const int hb = gn * 16 + l16;
        if (gn < 4) {                       // k columns 0..63
            #pragma unroll
            for (int rr2 = 0; rr2 < 4; rr2++) {
                const int row = row0 + quad * 4 + rr2;
                kO[(size_t)row * H_ + hb] = bf16_rne(acc[n][rr2]);
            }
        } else if (gn < 8) {                // q columns 0..63 (pre-scaled)
            #pragma unroll
            for (int rr2 = 0; rr2 < 4; rr2++) {
                const int row = row0 + quad * 4 + rr2;
                qO[(size_t)row * H_ + (hb - 64)] = bf16_rne(acc[n][rr2]);
            }
        } else {                            // v -> LDS tile [key-in-tile][h]
            #pragma unroll
            for (int rr2 = 0; rr2 < 4; rr2++)
                VL[rg * 16 + quad * 4 + rr2][(gn - 8) * 16 + l16] = bf16_rne(acc[n][rr2]);
        }
    }
    __syncthreads();

    // ---- epilogue part 2: gather permuted frags, coalesced Vf store ----
    if (t < 256) {
        const int g  = t >> 6;          // h-group 0..3
        const int lf = t & 15;
        const int qf = (t >> 4) & 3;
        unsigned pk[4];
        #pragma unroll
        for (int jj = 0; jj < 4; jj++) {
            const int p0 = qf * 8 + 2 * jj;
            const int i0 = (p0 >> 1) | ((p0 & 1) << 4);
            const int p1 = p0 + 1;
            const int i1 = (p1 >> 1) | ((p1 & 1) << 4);
            pk[jj] = (unsigned)VL[i0][g * 16 + lf]
                   | ((unsigned)VL[i1][g * 16 + lf] << 16);
        }
        const int tile = blockIdx.x;    // = b*64 + kt
        *(uint4*)(vfO + ((size_t)tile * 4 + g) * 512 + (size_t)(t & 63) * 8) =
            make_uint4(pk[0], pk[1], pk[2], pk[3]);
    }
}

// ====================================================================
// Kernel 2: MFMA flash attention (R5, unchanged): unnormalized exp2
// softmax, per-lane lsum, split-K x4 waves, fragment-major Vf loads.
// ====================================================================
__global__ __launch_bounds__(256, 4) void attn_mfma(
    const unsigned short* __restrict__ q,   // bf16 [B][T][H], pre-scaled
    const unsigned short* __restrict__ k,   // bf16 [B][T][H]
    const unsigned short* __restrict__ vf,  // bf16 fragment-major
    float* __restrict__ out)
{
    __shared__ unsigned short Pl[4][16 * 40];
    __shared__ float Ot[4][16][68];
    __shared__ float lsW[4][16];

    const int t    = threadIdx.x;
    const int w    = t >> 6;
    const int l    = t & 63;
    const int l16  = l & 15;
    const int quad = l >> 4;

    const int b    = blockIdx.x & 7;
    const int qidx = blockIdx.x >> 3;
    const int qt   = (qidx & 1) ? (127 - (qidx >> 1)) : (qidx >> 1);
    const int t0   = qt * 16;
    const int nk   = t0 / 32 + 1;

    const size_t qoff = ((size_t)b * T_ + t0 + l16) * H_ + quad * 8;
    bf16x8 aq0 = *(const bf16x8*)(q + qoff);
    bf16x8 aq1 = *(const bf16x8*)(q + qoff + 32);

    f32x4 o[4];
    #pragma unroll
    for (int g = 0; g < 4; g++) o[g] = (f32x4){0.f, 0.f, 0.f, 0.f};
    float ls[4] = {0.f, 0.f, 0.f, 0.f};

    const unsigned short* kbp = k + (size_t)b * T_ * H_;
    const unsigned short* vbp = vf + (size_t)b * 64 * 2048 + (size_t)l * 8;
    unsigned short* Pw = &Pl[w][0];

    bf16x8 bk00, bk01, bk10, bk11, bv0, bv1, bv2, bv3;
    if (w < nk) {
        const int kbase = w * 32;
        const unsigned short* kp = kbp + (size_t)(kbase + l16) * H_ + quad * 8;
        bk00 = *(const bf16x8*)(kp);
        bk01 = *(const bf16x8*)(kp + 32);
        bk10 = *(const bf16x8*)(kp + 16 * H_);
        bk11 = *(const bf16x8*)(kp + 16 * H_ + 32);
        const unsigned short* vp = vbp + (size_t)w * 2048;
        bv0 = *(const bf16x8*)(vp);
        bv1 = *(const bf16x8*)(vp + 512);
        bv2 = *(const bf16x8*)(vp + 1024);
        bv3 = *(const bf16x8*)(vp + 1536);
    }

    for (int kt = w; kt < nk; kt += 4) {
        const int ktn    = (kt + 4 < nk) ? kt + 4 : kt;
        const int kbasen = ktn * 32;
        const unsigned short* kpn = kbp + (size_t)(kbasen + l16) * H_ + quad * 8;
        bf16x8 nk00 = *(const bf16x8*)(kpn);
        bf16x8 nk01 = *(const bf16x8*)(kpn + 32);
        bf16x8 nk10 = *(const bf16x8*)(kpn + 16 * H_);
        bf16x8 nk11 = *(const bf16x8*)(kpn + 16 * H_ + 32);
        const unsigned short* vpn = vbp + (size_t)ktn * 2048;
        bf16x8 nv0 = *(const bf16x8*)(vpn);
        bf16x8 nv1 = *(const bf16x8*)(vpn + 512);
        bf16x8 nv2 = *(const bf16x8*)(vpn + 1024);
        bf16x8 nv3 = *(const bf16x8*)(vpn + 1536);

        const int kbase = kt * 32;
        f32x4 s0 = (f32x4){0.f, 0.f, 0.f, 0.f};
        f32x4 s1 = (f32x4){0.f, 0.f, 0.f, 0.f};
        s0 = __builtin_amdgcn_mfma_f32_16x16x32_bf16(aq0, bk00, s0, 0, 0, 0);
        s0 = __builtin_amdgcn_mfma_f32_16x16x32_bf16(aq1, bk01, s0, 0, 0, 0);
        s1 = __builtin_amdgcn_mfma_f32_16x16x32_bf16(aq0, bk10, s1, 0, 0, 0);
        s1 = __builtin_amdgcn_mfma_f32_16x16x32_bf16(aq1, bk11, s1, 0, 0, 0);

        if (kbase + 31 > t0) {
            const int rowb = t0 + quad * 4;
            #pragma unroll
            for (int r = 0; r < 4; r++) {
                if (kbase + l16 > rowb + r)      s0[r] = -3.0e38f;
                if (kbase + 16 + l16 > rowb + r) s1[r] = -3.0e38f;
            }
        }

        #pragma unroll
        for (int r = 0; r < 4; r++) {
            float p0 = exp2f(s0[r]);
            float p1 = exp2f(s1[r]);
            ls[r] += p0 + p1;
            *(unsigned*)(Pw + (quad * 4 + r) * 40 + 2 * l16) = pack_bf16x2(p0, p1);
        }
        asm volatile("s_waitcnt lgkmcnt(0)" ::: "memory");
        bf16x8 ap = *(const bf16x8*)(Pw + l16 * 40 + quad * 8);

        o[0] = __builtin_amdgcn_mfma_f32_16x16x32_bf16(ap, bv0, o[0], 0, 0, 0);
        o[1] = __builtin_amdgcn_mfma_f32_16x16x32_bf16(ap, bv1, o[1], 0, 0, 0);
        o[2] = __builtin_amdgcn_mfma_f32_16x16x32_bf16(ap, bv2, o[2], 0, 0, 0);
        o[3] = __builtin_amdgcn_mfma_f32_16x16x32_bf16(ap, bv3, o[3], 0, 0, 0);

        bk00 = nk00; bk01 = nk01; bk10 = nk10; bk11 = nk11;
        bv0 = nv0; bv1 = nv1; bv2 = nv2; bv3 = nv3;
    }

    #pragma unroll
    for (int r = 0; r < 4; r++) {
        float s = ls[r];
        s += __shfl_xor(s, 1);
        s += __shfl_xor(s, 2);
        s += __shfl_xor(s, 4);
        s += __shfl_xor(s, 8);
        ls[r] = s;
    }
    if (l16 == 0) {
        #pragma unroll
        for (int r = 0; r < 4; r++) lsW[w][quad * 4 + r] = ls[r];
    }
    #pragma unroll
    for (int g = 0; g < 4; g++)
        #pragma unroll
        for (int r = 0; r < 4; r++)
            Ot[w][quad * 4 + r][g * 16 + l16] = o[g][r];
    __syncthreads();

    {
        const int col = w * 16 + l16;
        #pragma unroll
        for (int r = 0; r < 4; r++) {
            const int row = quad * 4 + r;
            float L  = lsW[0][row] + lsW[1][row] + lsW[2][row] + lsW[3][row];
            float sv = Ot[0][row][col] + Ot[1][row][col]
                     + Ot[2][row][col] + Ot[3][row][col];
            out[((size_t)b * T_ + t0 + row) * H_ + col] = sv / L;
        }
    }
}

// ====================================================================
extern "C" void kernel_launch(void* const* d_in, const int* in_sizes, int n_in,
                              void* d_out, int out_size, void* d_ws, size_t ws_size,
                              hipStream_t stream)
{
    const float* x  = (const float*)d_in[0];
    const float* Wk = (const float*)d_in[1];
    const float* Wq = (const float*)d_in[2];
    const float* Wv = (const float*)d_in[3];

    // workspace: Wt (384KB) | k | q | vf (bf16, 2MB each)
    unsigned short* wt    = (unsigned short*)d_ws;
    unsigned short* kbuf  = wt + 24576 * 8;
    unsigned short* qbuf  = kbuf + BT * H_;
    unsigned short* vfbuf = qbuf + BT * H_;
    float* outp = (float*)d_out;

    wt_build_k<<<96, 256, 0, stream>>>(Wk, Wq, Wv, wt);
    qkv_mfma_k<<<(B_ * T_) / 32, 512, 0, stream>>>(x, wt, kbuf, qbuf, vfbuf);
    attn_mfma<<<B_ * 128, 256, 0, stream>>>(qbuf, kbuf, vfbuf, outp);
}

// Round 8
// 148.329 us; speedup vs baseline: 1.1376x; 1.0110x over previous
//
#include <hip/hip_runtime.h>
#include <math.h>

// Problem constants (B,T,E,H fixed by setup_inputs).
constexpr int B_ = 8, T_ = 2048, E_ = 1024, H_ = 64;
constexpr long BT = (long)B_ * T_;   // 16384 rows

typedef __attribute__((ext_vector_type(8))) short bf16x8;   // 8 bf16 (4 VGPRs)
typedef __attribute__((ext_vector_type(4))) float f32x4;    // MFMA 16x16 acc

__device__ inline unsigned short bf16_rne(float f) {
    union { float f; unsigned u; } v; v.f = f;
    unsigned u = v.u + (0x7FFFu + ((v.u >> 16) & 1u));
    return (unsigned short)(u >> 16);
}
__device__ inline unsigned pack_bf16x2(float lo, float hi) {
    return (unsigned)bf16_rne(lo) | ((unsigned)bf16_rne(hi) << 16);
}

// Async global->LDS DMA, 16B per lane. LDS dest = wave-uniform base +
// lane*16 (HW requirement); global addr may be fully lane-divergent.
__device__ inline void load_lds16(const void* g, void* l) {
    __builtin_amdgcn_global_load_lds(
        (const __attribute__((address_space(1))) void*)(uintptr_t)g,
        (__attribute__((address_space(3))) void*)(unsigned)(uintptr_t)l,
        16, 0, 0);
}

constexpr float QS = 0.18033688011112042f;   // H^-0.5 * log2(e), folded into Wq

// ====================================================================
// Kernel 0: build B-frag-ready transposed bf16 weight buffer. (R3)
// ====================================================================
__global__ __launch_bounds__(256) void wt_build_k(
    const float* __restrict__ Wk, const float* __restrict__ Wq,
    const float* __restrict__ Wv, unsigned short* __restrict__ Wt)
{
    const int d    = blockIdx.x * 256 + threadIdx.x;   // 0..24575
    const int tile = d >> 6;
    const int lq   = d & 63;
    const int quad = lq >> 4;
    const int l16  = lq & 15;
    const int kc   = tile / 12;
    const int nt   = tile - kc * 12;
    const int n    = nt * 16 + l16;

    const float* src; int col; float s = 1.0f;
    if (n < 64)       { src = Wk; col = n; }
    else if (n < 128) { src = Wq; col = n - 64; s = QS; }
    else              { src = Wv; col = n - 128; }

    const int kk0 = kc * 32 + quad * 8;
    const float* sp = src + (size_t)kk0 * H_ + col;
    unsigned p[4];
    #pragma unroll
    for (int jj = 0; jj < 4; jj++)
        p[jj] = pack_bf16x2(sp[(2 * jj) * H_] * s, sp[(2 * jj + 1) * H_] * s);
    *(uint4*)(Wt + (size_t)d * 8) = make_uint4(p[0], p[1], p[2], p[3]);
}

// ====================================================================
// Kernel 1: MFMA QKV projection, R7 (unchanged): global_load_lds
// staged x, double-buffered, chunk-XOR swizzle; Wt b-frags from L2.
// ====================================================================
__global__ __launch_bounds__(512, 4) void qkv_mfma_k(
    const float* __restrict__ x, const unsigned short* __restrict__ Wt,
    unsigned short* __restrict__ kO, unsigned short* __restrict__ qO,
    unsigned short* __restrict__ vfO)
{
    __shared__ float4 xs[2][32][16];        // 16 KB: [buf][row][chunk], swizzled
    __shared__ unsigned short VL[32][66];   // V tile staging (pad 66)

    const int t    = threadIdx.x;           // 0..511
    const int w    = t >> 6;                // 0..7
    const int l    = t & 63;
    const int l16  = l & 15;
    const int quad = l >> 4;
    const int rg   = w >> 2;                // row-group 0..1
    const int nq   = w & 3;                 // n-quarter 0..3 (3 tiles each)
    const int row0 = blockIdx.x * 32 + rg * 16;
    const int row0b = blockIdx.x * 32;

    const int rr = w * 4 + (l >> 4);        // staged row 0..31
    const int cc = l & 15;                  // LDS chunk slot
    const int gg = cc ^ (rr & 7);           // global chunk fetched (swizzle)
    const float* gsrc = x + (size_t)(row0b + rr) * E_ + gg * 4;

    const int r  = rg * 16 + l16;           // A-frag row in tile
    const int rx = r & 7;                   // swizzle key

    f32x4 acc[3];
    #pragma unroll
    for (int n = 0; n < 3; n++) acc[n] = (f32x4){0.f, 0.f, 0.f, 0.f};

    load_lds16(gsrc, &xs[0][rr][cc]);       // stage tile 0

    for (int it = 0; it < 16; ++it) {
        const int buf = it & 1;
        __syncthreads();                    // drains tile-it DMA + prev reads
        if (it + 1 < 16)
            load_lds16(gsrc + (it + 1) * 64, &xs[buf ^ 1][rr][cc]);

        #pragma unroll
        for (int kk = 0; kk < 2; ++kk) {
            const int G0 = kk * 8 + quad * 2;
            float4 fa = xs[buf][r][G0 ^ rx];
            float4 fb = xs[buf][r][(G0 + 1) ^ rx];

            const int kc = it * 2 + kk;
            const unsigned short* wpp = Wt + (size_t)(kc * 12 + nq * 3) * 512 + (size_t)l * 8;
            bf16x8 b0 = *(const bf16x8*)(wpp);
            bf16x8 b1 = *(const bf16x8*)(wpp + 512);
            bf16x8 b2 = *(const bf16x8*)(wpp + 1024);

            union { bf16x8 v; unsigned u[4]; } av;
            av.u[0] = pack_bf16x2(fa.x, fa.y);
            av.u[1] = pack_bf16x2(fa.z, fa.w);
            av.u[2] = pack_bf16x2(fb.x, fb.y);
            av.u[3] = pack_bf16x2(fb.z, fb.w);

            acc[0] = __builtin_amdgcn_mfma_f32_16x16x32_bf16(av.v, b0, acc[0], 0, 0, 0);
            acc[1] = __builtin_amdgcn_mfma_f32_16x16x32_bf16(av.v, b1, acc[1], 0, 0, 0);
            acc[2] = __builtin_amdgcn_mfma_f32_16x16x32_bf16(av.v, b2, acc[2], 0, 0, 0);
        }
    }

    // ---- epilogue part 1: k/q global stores, v -> LDS staging ----
    #pragma unroll
    for (int n = 0; n < 3; n++) {
        const int gn = nq * 3 + n;          // 0..11
        const int hb = gn * 16 + l16;
        if (gn < 4) {                       // k columns 0..63
            #pragma unroll
            for (int rr2 = 0; rr2 < 4; rr2++) {
                const int row = row0 + quad * 4 + rr2;
                kO[(size_t)row * H_ + hb] = bf16_rne(acc[n][rr2]);
            }
        } else if (gn < 8) {                // q columns 0..63 (pre-scaled)
            #pragma unroll
            for (int rr2 = 0; rr2 < 4; rr2++) {
                const int row = row0 + quad * 4 + rr2;
                qO[(size_t)row * H_ + (hb - 64)] = bf16_rne(acc[n][rr2]);
            }
        } else {                            // v -> LDS tile [key-in-tile][h]
            #pragma unroll
            for (int rr2 = 0; rr2 < 4; rr2++)
                VL[rg * 16 + quad * 4 + rr2][(gn - 8) * 16 + l16] = bf16_rne(acc[n][rr2]);
        }
    }
    __syncthreads();

    // ---- epilogue part 2: gather permuted frags, coalesced Vf store ----
    if (t < 256) {
        const int g  = t >> 6;          // h-group 0..3
        const int lf = t & 15;
        const int qf = (t >> 4) & 3;
        unsigned pk[4];
        #pragma unroll
        for (int jj = 0; jj < 4; jj++) {
            const int p0 = qf * 8 + 2 * jj;
            const int i0 = (p0 >> 1) | ((p0 & 1) << 4);
            const int p1 = p0 + 1;
            const int i1 = (p1 >> 1) | ((p1 & 1) << 4);
            pk[jj] = (unsigned)VL[i0][g * 16 + lf]
                   | ((unsigned)VL[i1][g * 16 + lf] << 16);
        }
        const int tile = blockIdx.x;    // = b*64 + kt
        *(uint4*)(vfO + ((size_t)tile * 4 + g) * 512 + (size_t)(t & 63) * 8) =
            make_uint4(pk[0], pk[1], pk[2], pk[3]);
    }
}

// ====================================================================
// Kernel 2: MFMA flash attention, R8: DMA-staged K/V double buffer.
// R5/R6 proved the compiler sinks register prefetch -> serial memory
// round-trips per k-tile (85% idle in R4 counters). Fix: per-wave
// global_load_lds staging (un-sinkable). Each iter: issue tile t+1's
// 8x1KB DMAs -> s_waitcnt vmcnt(8) (waits tile t only; new 8 stay in
// flight across compute) -> ds_read_b128 frags -> QK MFMA -> exp2 ->
// P LDS round-trip -> PV MFMA. No __syncthreads in the loop (buffers
// are wave-private; WAR safe: iter i's ds_reads complete before its
// PV MFMAs issue, which precede iter i+1's DMA issue).
// LDS: KV 4x2x8KB = 64 KB (re-aliased as merge buffer after barrier;
// each wave exits with vmcnt(0)) + P 5 KB -> 2 blocks/CU.
// ====================================================================
__global__ __launch_bounds__(256, 2) void attn_mfma(
    const unsigned short* __restrict__ q,   // bf16 [B][T][H], pre-scaled
    const unsigned short* __restrict__ k,   // bf16 [B][T][H]
    const unsigned short* __restrict__ vf,  // bf16 fragment-major
    float* __restrict__ out)
{
    __shared__ __align__(16) unsigned short KV[4][2][4096];  // 64 KB
    __shared__ unsigned short Pl[4][16 * 40];                // 5 KB

    const int t    = threadIdx.x;
    const int w    = t >> 6;
    const int l    = t & 63;
    const int l16  = l & 15;
    const int quad = l >> 4;

    const int b    = blockIdx.x & 7;
    const int qidx = blockIdx.x >> 3;
    const int qt   = (qidx & 1) ? (127 - (qidx >> 1)) : (qidx >> 1);
    const int t0   = qt * 16;
    const int nk   = t0 / 32 + 1;

    const size_t qoff = ((size_t)b * T_ + t0 + l16) * H_ + quad * 8;
    bf16x8 aq0 = *(const bf16x8*)(q + qoff);
    bf16x8 aq1 = *(const bf16x8*)(q + qoff + 32);

    f32x4 o[4];
    #pragma unroll
    for (int g = 0; g < 4; g++) o[g] = (f32x4){0.f, 0.f, 0.f, 0.f};
    float ls[4] = {0.f, 0.f, 0.f, 0.f};

    const unsigned short* kbp = k  + (size_t)b * T_ * H_;
    const unsigned short* vfb = vf + (size_t)b * 64 * 2048;
    unsigned short* Pw = &Pl[w][0];
    unsigned short* kv0 = &KV[w][0][0];
    unsigned short* kv1 = &KV[w][1][0];

    // stage tile kt into dst: 4 K-frags + 4 V-frags, 1KB each
    auto issue_tile = [&](int kt, unsigned short* dst) {
        const int kbase = kt * 32;
        const unsigned short* kp = kbp + (size_t)(kbase + l16) * H_ + quad * 8;
        load_lds16(kp,               dst + 0 * 512 + l * 8);
        load_lds16(kp + 32,          dst + 1 * 512 + l * 8);
        load_lds16(kp + 16 * H_,     dst + 2 * 512 + l * 8);
        load_lds16(kp + 16 * H_ + 32, dst + 3 * 512 + l * 8);
        const unsigned short* vp = vfb + (size_t)kt * 2048 + l * 8;
        load_lds16(vp,        dst + 4 * 512 + l * 8);
        load_lds16(vp + 512,  dst + 5 * 512 + l * 8);
        load_lds16(vp + 1024, dst + 6 * 512 + l * 8);
        load_lds16(vp + 1536, dst + 7 * 512 + l * 8);
    };

    if (w < nk) issue_tile(w, kv0);

    int it = 0;
    for (int kt = w; kt < nk; kt += 4, ++it) {
        unsigned short* cur = (it & 1) ? kv1 : kv0;
        unsigned short* nxt = (it & 1) ? kv0 : kv1;
        if (kt + 4 < nk) {
            issue_tile(kt + 4, nxt);
            asm volatile("s_waitcnt vmcnt(8)" ::: "memory");   // tile kt done
        } else {
            asm volatile("s_waitcnt vmcnt(0)" ::: "memory");
        }

        bf16x8 bk00 = *(const bf16x8*)(cur + 0 * 512 + l * 8);
        bf16x8 bk01 = *(const bf16x8*)(cur + 1 * 512 + l * 8);
        bf16x8 bk10 = *(const bf16x8*)(cur + 2 * 512 + l * 8);
        bf16x8 bk11 = *(const bf16x8*)(cur + 3 * 512 + l * 8);
        bf16x8 bv0  = *(const bf16x8*)(cur + 4 * 512 + l * 8);
        bf16x8 bv1  = *(const bf16x8*)(cur + 5 * 512 + l * 8);
        bf16x8 bv2  = *(const bf16x8*)(cur + 6 * 512 + l * 8);
        bf16x8 bv3  = *(const bf16x8*)(cur + 7 * 512 + l * 8);

        const int kbase = kt * 32;
        f32x4 s0 = (f32x4){0.f, 0.f, 0.f, 0.f};
        f32x4 s1 = (f32x4){0.f, 0.f, 0.f, 0.f};
        s0 = __builtin_amdgcn_mfma_f32_16x16x32_bf16(aq0, bk00, s0, 0, 0, 0);
        s0 = __builtin_amdgcn_mfma_f32_16x16x32_bf16(aq1, bk01, s0, 0, 0, 0);
        s1 = __builtin_amdgcn_mfma_f32_16x16x32_bf16(aq0, bk10, s1, 0, 0, 0);
        s1 = __builtin_amdgcn_mfma_f32_16x16x32_bf16(aq1, bk11, s1, 0, 0, 0);

        if (kbase + 31 > t0) {   // diagonal tile: causal mask
            const int rowb = t0 + quad * 4;
            #pragma unroll
            for (int r = 0; r < 4; r++) {
                if (kbase + l16 > rowb + r)      s0[r] = -3.0e38f;
                if (kbase + 16 + l16 > rowb + r) s1[r] = -3.0e38f;
            }
        }

        #pragma unroll
        for (int r = 0; r < 4; r++) {
            float p0 = exp2f(s0[r]);
            float p1 = exp2f(s1[r]);
            ls[r] += p0 + p1;
            *(unsigned*)(Pw + (quad * 4 + r) * 40 + 2 * l16) = pack_bf16x2(p0, p1);
        }
        asm volatile("s_waitcnt lgkmcnt(0)" ::: "memory");   // wave-local
        bf16x8 ap = *(const bf16x8*)(Pw + l16 * 40 + quad * 8);

        o[0] = __builtin_amdgcn_mfma_f32_16x16x32_bf16(ap, bv0, o[0], 0, 0, 0);
        o[1] = __builtin_amdgcn_mfma_f32_16x16x32_bf16(ap, bv1, o[1], 0, 0, 0);
        o[2] = __builtin_amdgcn_mfma_f32_16x16x32_bf16(ap, bv2, o[2], 0, 0, 0);
        o[3] = __builtin_amdgcn_mfma_f32_16x16x32_bf16(ap, bv3, o[3], 0, 0, 0);
    }

    // ---- once-per-wave lsum row reduction (16-lane groups) ----
    #pragma unroll
    for (int r = 0; r < 4; r++) {
        float s = ls[r];
        s += __shfl_xor(s, 1);
        s += __shfl_xor(s, 2);
        s += __shfl_xor(s, 4);
        s += __shfl_xor(s, 8);
        ls[r] = s;
    }

    // ---- merge: re-alias KV region (all waves at vmcnt(0) past loop) ----
    __syncthreads();
    float* otb = (float*)&KV[0][0][0];          // Ot[w][16][68] floats
    float* lsW = otb + 4 * 16 * 68;             // + lsW[4][16]
    if (l16 == 0) {
        #pragma unroll
        for (int r = 0; r < 4; r++) lsW[w * 16 + quad * 4 + r] = ls[r];
    }
    #pragma unroll
    for (int g = 0; g < 4; g++)
        #pragma unroll
        for (int r = 0; r < 4; r++)
            otb[((w * 16) + quad * 4 + r) * 68 + g * 16 + l16] = o[g][r];
    __syncthreads();

    {
        const int col = w * 16 + l16;
        #pragma unroll
        for (int r = 0; r < 4; r++) {
            const int row = quad * 4 + r;
            float L  = lsW[0 * 16 + row] + lsW[1 * 16 + row]
                     + lsW[2 * 16 + row] + lsW[3 * 16 + row];
            float sv = otb[(0 * 16 + row) * 68 + col] + otb[(1 * 16 + row) * 68 + col]
                     + otb[(2 * 16 + row) * 68 + col] + otb[(3 * 16 + row) * 68 + col];
            out[((size_t)b * T_ + t0 + row) * H_ + col] = sv / L;
        }
    }
}

// ====================================================================
extern "C" void kernel_launch(void* const* d_in, const int* in_sizes, int n_in,
                              void* d_out, int out_size, void* d_ws, size_t ws_size,
                              hipStream_t stream)
{
    const float* x  = (const float*)d_in[0];
    const float* Wk = (const float*)d_in[1];
    const float* Wq = (const float*)d_in[2];
    const float* Wv = (const float*)d_in[3];

    // workspace: Wt (384KB) | k | q | vf (bf16, 2MB each)
    unsigned short* wt    = (unsigned short*)d_ws;
    unsigned short* kbuf  = wt + 24576 * 8;
    unsigned short* qbuf  = kbuf + BT * H_;
    unsigned short* vfbuf = qbuf + BT * H_;
    float* outp = (float*)d_out;

    wt_build_k<<<96, 256, 0, stream>>>(Wk, Wq, Wv, wt);
    qkv_mfma_k<<<(B_ * T_) / 32, 512, 0, stream>>>(x, wt, kbuf, qbuf, vfbuf);
    attn_mfma<<<B_ * 128, 256, 0, stream>>>(qbuf, kbuf, vfbuf, outp);
}